// Round 5
// baseline (7098.129 us; speedup 1.0000x reference)
//
#include <hip/hip_runtime.h>
#include <hip/hip_bf16.h>

#define U_CNT 100000
#define I_CNT 50000
#define N_CNT 150000
#define NNZ_CNT 6000000
#define BKT_ROWS 128
#define NBKT 1172                 // ceil(150000/128)
#define OFFW (NBKT + 1)           // 1173
#define CHUNK 4096
#define NBLK_BIN 1465             // ceil(6M/4096)
#define COL_MASK 0x3FFFF          // 18 bits (N=150000 < 2^18)

// ---------------------------------------------------------------------------
// bin_sort: per-block LDS counting sort by bucket (row>>7); writes the block's
// 4096 records BLOCK-MAJOR (private contiguous 32KB region -> full-line,
// write-once, zero RMW amplification). Also: offM[g][b] = absolute start of
// block g's bucket-b segment, and global bucket counts bcnt.
// ---------------------------------------------------------------------------
__global__ __launch_bounds__(1024) void bin_sort_kernel(
    const int* __restrict__ erow, const int* __restrict__ ecol,
    const float* __restrict__ evalv, int* __restrict__ bcnt,
    int2* __restrict__ recs_bm, int* __restrict__ offM)
{
    __shared__ int2 stage[CHUNK];       // 32 KB; reused as scan temp (int*)
    __shared__ int  hist[NBKT];
    __shared__ int  lbase[NBKT];

    int t = threadIdx.x;
    int g = blockIdx.x;
    int base = g * CHUNK;
    int n = NNZ_CNT - base; if (n > CHUNK) n = CHUNK;

    int rows[4], cols[4]; float vals[4];
#pragma unroll
    for (int k = 0; k < 4; ++k) {
        int e = base + k * 1024 + t;
        bool ok = (e < NNZ_CNT);
        rows[k] = ok ? erow[e] : -1;
        cols[k] = ok ? ecol[e] : 0;
        vals[k] = ok ? evalv[e] : 0.f;
    }

    for (int i = t; i < NBKT; i += 1024) hist[i] = 0;
    __syncthreads();
#pragma unroll
    for (int k = 0; k < 4; ++k)
        if (rows[k] >= 0) atomicAdd(&hist[rows[k] >> 7], 1);
    __syncthreads();

    // global bucket counts
    for (int i = t; i < NBKT; i += 1024)
        if (hist[i]) atomicAdd(&bcnt[i], hist[i]);

    // exclusive scan of hist (2048-wide two-half Hillis in stage temp)
    int* sc = (int*)stage;
    int v0 = (t < NBKT) ? hist[t] : 0;
    int v1 = (1024 + t < NBKT) ? hist[1024 + t] : 0;
    sc[t] = v0; sc[1024 + t] = v1;
    __syncthreads();
    for (int off = 1; off < 1024; off <<= 1) {
        int u0 = (t >= off) ? sc[t - off] : 0;
        int u1 = (t >= off) ? sc[1024 + t - off] : 0;
        __syncthreads();
        sc[t] += u0; sc[1024 + t] += u1;
        __syncthreads();
    }
    int tot0 = sc[1023];
    if (t < NBKT) lbase[t] = sc[t] - v0;
    if (1024 + t < NBKT) lbase[1024 + t] = tot0 + sc[1024 + t] - v1;
    __syncthreads();

    // reset hist as scatter cursors
    for (int i = t; i < NBKT; i += 1024) hist[i] = 0;
    __syncthreads();

    // scatter into LDS stage (bucket-major within block)
#pragma unroll
    for (int k = 0; k < 4; ++k) {
        if (rows[k] >= 0) {
            int b = rows[k] >> 7;
            int p = lbase[b] + atomicAdd(&hist[b], 1);
            int pack = ((rows[k] & (BKT_ROWS - 1)) << 18) | cols[k];
            stage[p] = make_int2(pack, __float_as_int(vals[k]));
        }
    }
    __syncthreads();

    // stream out block's private region (coalesced, full lines)
    for (int i = t; i < n; i += 1024) recs_bm[base + i] = stage[i];

    // offsets
    for (int i = t; i < NBKT; i += 1024)
        offM[(size_t)g * OFFW + i] = base + lbase[i];
    if (t == 0) offM[(size_t)g * OFFW + NBKT] = base + n;
}

// ---------------------------------------------------------------------------
// bucket_scan: exclusive scan of bcnt[1172] -> bbase[1173] (sentinel = NNZ)
// ---------------------------------------------------------------------------
__global__ __launch_bounds__(1024) void bucket_scan_kernel(
    const int* __restrict__ bcnt, int* __restrict__ bbase)
{
    __shared__ int s0[1024], s1[1024];
    int t = threadIdx.x;
    int v0 = (t < NBKT) ? bcnt[t] : 0;
    int v1 = (1024 + t < NBKT) ? bcnt[1024 + t] : 0;
    s0[t] = v0; s1[t] = v1;
    __syncthreads();
    for (int off = 1; off < 1024; off <<= 1) {
        int u0 = (t >= off) ? s0[t - off] : 0;
        int u1 = (t >= off) ? s1[t - off] : 0;
        __syncthreads();
        s0[t] += u0; s1[t] += u1;
        __syncthreads();
    }
    int tot0 = s0[1023];
    if (t < NBKT) bbase[t] = s0[t] - v0;
    if (1024 + t < NBKT) bbase[1024 + t] = tot0 + s1[t] - v1;
    if (t == 0) bbase[NBKT] = tot0 + s1[1023];
}

// ---------------------------------------------------------------------------
// compact: one block per bucket; gather the bucket's 1465 block-major segments
// into a bucket-contiguous record array. Writes block-exclusive & contiguous.
// ---------------------------------------------------------------------------
__global__ __launch_bounds__(1024) void compact_kernel(
    const int2* __restrict__ recs_bm, const int* __restrict__ offM,
    const int* __restrict__ bbase, int2* __restrict__ recs)
{
    __shared__ int slen[2048];
    int b = blockIdx.x;
    int t = threadIdx.x;

    for (int g = t; g < 2048; g += 1024) {
        int L = 0;
        if (g < NBLK_BIN) {
            size_t o = (size_t)g * OFFW + b;
            L = offM[o + 1] - offM[o];
        }
        slen[g] = L;
    }
    __syncthreads();
    // inclusive scan (two halves + fixup)
    for (int off = 1; off < 1024; off <<= 1) {
        int u0 = (t >= off) ? slen[t - off] : 0;
        int u1 = (t >= off) ? slen[1024 + t - off] : 0;
        __syncthreads();
        slen[t] += u0; slen[1024 + t] += u1;
        __syncthreads();
    }
    int tot0 = slen[1023];
    __syncthreads();
    slen[1024 + t] += tot0;
    __syncthreads();

    int dstbase = bbase[b];
    int wid = t >> 6, lane = t & 63;
    for (int g = wid; g < NBLK_BIN; g += 16) {
        size_t o = (size_t)g * OFFW + b;
        int s = offM[o], e = offM[o + 1];
        int d = dstbase + ((g == 0) ? 0 : slen[g - 1]);
        for (int r = lane; r < e - s; r += 64)
            recs[d + r] = recs_bm[s + r];
    }
}

// ---------------------------------------------------------------------------
// spmm_bucket: block = one 128-row bucket, 32KB LDS accumulator.
// Waves stream 64-record chunks: coalesced lane-load + shfl broadcast;
// lane = feature dim; ds_add_f32 accumulate (2-way bank alias = free).
// mode: 0 = y & acc=, 1 = y & acc+=, 2 = acc+= only.
// ---------------------------------------------------------------------------
__global__ __launch_bounds__(512) void spmm_bucket_kernel(
    const int* __restrict__ bbase, const int2* __restrict__ recs,
    const float* __restrict__ x, float* __restrict__ y,
    float* __restrict__ acc, int mode)
{
    __shared__ float lacc[BKT_ROWS * 64];   // 32 KB
    int b = blockIdx.x;
    int t = threadIdx.x;
    int wid = t >> 6, lane = t & 63;

    for (int i = t; i < BKT_ROWS * 64; i += 512) lacc[i] = 0.f;
    __syncthreads();

    int s = bbase[b], e = bbase[b + 1];
    int nchunk = (e - s + 63) >> 6;

    for (int c = wid; c < nchunk; c += 8) {
        int o = s + (c << 6);
        int m = e - o; if (m > 64) m = 64;
        int2 rec = (lane < m) ? recs[o + lane] : make_int2(0, 0);
        if (m == 64) {
#pragma unroll 8
            for (int j = 0; j < 64; ++j) {
                int pk = __shfl(rec.x, j);
                float v = __int_as_float(__shfl(rec.y, j));
                int col = pk & COL_MASK;
                int lr  = pk >> 18;
                float xv = x[(size_t)col * 64 + lane];
                atomicAdd(&lacc[(lr << 6) + lane], v * xv);
            }
        } else {
            for (int j = 0; j < m; ++j) {
                int pk = __shfl(rec.x, j);
                float v = __int_as_float(__shfl(rec.y, j));
                int col = pk & COL_MASK;
                int lr  = pk >> 18;
                float xv = x[(size_t)col * 64 + lane];
                atomicAdd(&lacc[(lr << 6) + lane], v * xv);
            }
        }
    }
    __syncthreads();

    int rowbase = b << 7;
    for (int i = t; i < BKT_ROWS * 64; i += 512) {
        int r = rowbase + (i >> 6);
        if (r < N_CNT) {
            size_t o = (size_t)r * 64 + (i & 63);
            float sv = lacc[i];
            if (mode == 0)      { y[o] = sv; acc[o] = sv; }
            else if (mode == 1) { y[o] = sv; acc[o] += sv; }
            else                {            acc[o] += sv; }
        }
    }
}

// ---------------------------------------------------------------------------
// Fused 2-layer MLP, wave per row; W1/W2 transposed in LDS.
// ---------------------------------------------------------------------------
__global__ __launch_bounds__(256) void mlp2_kernel(
    const float* __restrict__ xin, int nrows, float scale,
    const float* __restrict__ W1, const float* __restrict__ b1,
    const float* __restrict__ W2, const float* __restrict__ b2,
    float* __restrict__ out)
{
    __shared__ float W1T[64 * 64];
    __shared__ float W2T[64 * 64];
    __shared__ float rowbuf[4][64];
    __shared__ float hbuf[4][64];

    int t = threadIdx.x;
    for (int idx = t; idx < 4096; idx += 256) {
        int k = idx >> 6;
        int d = idx & 63;
        W1T[idx] = W1[d * 64 + k];
        W2T[idx] = W2[d * 64 + k];
    }
    __syncthreads();

    int wave = t >> 6;
    int lane = t & 63;
    float bb1 = b1[lane];
    float bb2 = b2[lane];

    for (int r = blockIdx.x * 4 + wave; r < nrows; r += gridDim.x * 4) {
        float xv = xin[(size_t)r * 64 + lane] * scale;
        rowbuf[wave][lane] = xv;
        float h = bb1;
#pragma unroll
        for (int k = 0; k < 64; ++k)
            h += rowbuf[wave][k] * W1T[k * 64 + lane];
        h = fmaxf(h, 0.f);
        hbuf[wave][lane] = h;
        float y = bb2;
#pragma unroll
        for (int k = 0; k < 64; ++k)
            y += hbuf[wave][k] * W2T[k * 64 + lane];
        out[(size_t)r * 64 + lane] = y;
    }
}

// ---------------------------------------------------------------------------

static inline int imin(int a, int b) { return a < b ? a : b; }

extern "C" void kernel_launch(void* const* d_in, const int* in_sizes, int n_in,
                              void* d_out, int out_size, void* d_ws, size_t ws_size,
                              hipStream_t stream)
{
    (void)in_sizes; (void)n_in; (void)out_size; (void)ws_size;

    const float* user_emb = (const float*)d_in[0];
    const float* item_emb = (const float*)d_in[1];
    const int*   erow     = (const int*)d_in[2];
    const int*   ecol     = (const int*)d_in[3];
    const float* evalv    = (const float*)d_in[4];
    const float* Wsg1 = (const float*)d_in[5];
    const float* bsg1 = (const float*)d_in[6];
    const float* Wsg2 = (const float*)d_in[7];
    const float* bsg2 = (const float*)d_in[8];
    const float* Wuf1 = (const float*)d_in[9];
    const float* buf1 = (const float*)d_in[10];
    const float* Wuf2 = (const float*)d_in[11];
    const float* buf2 = (const float*)d_in[12];
    const float* Wif1 = (const float*)d_in[13];
    const float* bif1 = (const float*)d_in[14];
    const float* Wif2 = (const float*)d_in[15];
    const float* bif2 = (const float*)d_in[16];

    float* out = (float*)d_out;
    const size_t XB = (size_t)N_CNT * 64;   // 9.6M floats

    // d_out transient region (dead before the x0 copy):
    //   recs_bm: 6M int2 (48 MB) | offM: 1465*1173 ints (6.87 MB)
    int2* recs_bm = (int2*)out;
    int*  offM    = (int*)(out + 12000000);

    // workspace (~86.4 MB):
    char* ws = (char*)d_ws;
    float* acc   = (float*)ws;                                    // 9.6M floats
    int2*  recs  = (int2*)(ws + XB * 4);                          // 6M int2
    int*   bcnt  = (int*)(ws + XB * 4 + (size_t)NNZ_CNT * 8);     // 1172
    int*   bbase = bcnt + 1280;                                   // 1173

    float* xA = out;
    float* xB = out + XB;

    // ---- build bucket-sorted records ----
    hipMemsetAsync(bcnt, 0, NBKT * sizeof(int), stream);
    bin_sort_kernel<<<NBLK_BIN, 1024, 0, stream>>>(erow, ecol, evalv, bcnt, recs_bm, offM);
    bucket_scan_kernel<<<1, 1024, 0, stream>>>(bcnt, bbase);
    compact_kernel<<<NBKT, 1024, 0, stream>>>(recs_bm, offM, bbase, recs);

    // ---- x0 = concat(user_emb, item_emb) (overwrites transient region) ----
    hipMemcpyAsync(xA, user_emb, (size_t)U_CNT * 64 * 4, hipMemcpyDeviceToDevice, stream);
    hipMemcpyAsync(xA + (size_t)U_CNT * 64, item_emb, (size_t)I_CNT * 64 * 4,
                   hipMemcpyDeviceToDevice, stream);

    // ---- 3 propagation layers, accumulate into acc ----
    spmm_bucket_kernel<<<NBKT, 512, 0, stream>>>(bbase, recs, xA, xB, acc, 0);
    spmm_bucket_kernel<<<NBKT, 512, 0, stream>>>(bbase, recs, xB, xA, acc, 1);
    spmm_bucket_kernel<<<NBKT, 512, 0, stream>>>(bbase, recs, xA, xB, acc, 2);

    // ---- MLP heads ----
    const float sc = 1.0f / 3.0f;
    int gb;
    gb = imin(1024, (N_CNT + 3) / 4);
    mlp2_kernel<<<gb, 256, 0, stream>>>(acc, N_CNT, sc, Wsg1, bsg1, Wsg2, bsg2, out);
    gb = imin(1024, (U_CNT + 3) / 4);
    mlp2_kernel<<<gb, 256, 0, stream>>>(acc, U_CNT, sc, Wuf1, buf1, Wuf2, buf2, out + XB);
    gb = imin(1024, (I_CNT + 3) / 4);
    mlp2_kernel<<<gb, 256, 0, stream>>>(acc + (size_t)U_CNT * 64, I_CNT, sc,
                                        Wif1, bif1, Wif2, bif2, out + XB + (size_t)U_CNT * 64);
}

// Round 6
// 1227.418 us; speedup vs baseline: 5.7830x; 5.7830x over previous
//
#include <hip/hip_runtime.h>
#include <hip/hip_bf16.h>

#define U_CNT 100000
#define I_CNT 50000
#define N_CNT 150000
#define NNZ_CNT 6000000
#define BKT_ROWS 128
#define NBKT 1172                 // ceil(150000/128)
#define OFFW (NBKT + 1)           // 1173
#define CHUNK 4096
#define NBLK_BIN 1465             // ceil(6M/4096)
#define COL_MASK 0x3FFFF          // 18 bits (N=150000 < 2^18)

// ---------------------------------------------------------------------------
// bin_sort: per-block LDS counting sort by bucket (row>>7); writes the block's
// 4096 records BLOCK-MAJOR into a private contiguous 32KB region -> full-line,
// write-once, zero RMW amplification. offM[g][b] = abs start of block g's
// bucket-b segment (sentinel at b=NBKT).
// ---------------------------------------------------------------------------
__global__ __launch_bounds__(1024) void bin_sort_kernel(
    const int* __restrict__ erow, const int* __restrict__ ecol,
    const float* __restrict__ evalv,
    int2* __restrict__ recs_bm, int* __restrict__ offM)
{
    __shared__ int2 stage[CHUNK];       // 32 KB; low 8KB reused as scan temp
    __shared__ int  hist[NBKT];
    __shared__ int  lbase[NBKT];

    int t = threadIdx.x;
    int g = blockIdx.x;
    int base = g * CHUNK;
    int n = NNZ_CNT - base; if (n > CHUNK) n = CHUNK;

    int rows[4], cols[4]; float vals[4];
#pragma unroll
    for (int k = 0; k < 4; ++k) {
        int e = base + k * 1024 + t;
        bool ok = (e < NNZ_CNT);
        rows[k] = ok ? erow[e] : -1;
        cols[k] = ok ? ecol[e] : 0;
        vals[k] = ok ? evalv[e] : 0.f;
    }

    for (int i = t; i < NBKT; i += 1024) hist[i] = 0;
    __syncthreads();
#pragma unroll
    for (int k = 0; k < 4; ++k)
        if (rows[k] >= 0) atomicAdd(&hist[rows[k] >> 7], 1);
    __syncthreads();

    // exclusive scan of hist (2048-wide two-half Hillis in stage temp)
    int* sc = (int*)stage;
    int v0 = (t < NBKT) ? hist[t] : 0;
    int v1 = (1024 + t < NBKT) ? hist[1024 + t] : 0;
    sc[t] = v0; sc[1024 + t] = v1;
    __syncthreads();
    for (int off = 1; off < 1024; off <<= 1) {
        int u0 = (t >= off) ? sc[t - off] : 0;
        int u1 = (t >= off) ? sc[1024 + t - off] : 0;
        __syncthreads();
        sc[t] += u0; sc[1024 + t] += u1;
        __syncthreads();
    }
    int tot0 = sc[1023];
    if (t < NBKT) lbase[t] = sc[t] - v0;
    if (1024 + t < NBKT) lbase[1024 + t] = tot0 + sc[1024 + t] - v1;
    __syncthreads();

    // reset hist as scatter cursors
    for (int i = t; i < NBKT; i += 1024) hist[i] = 0;
    __syncthreads();

    // scatter into LDS stage (bucket-major within block)
#pragma unroll
    for (int k = 0; k < 4; ++k) {
        if (rows[k] >= 0) {
            int b = rows[k] >> 7;
            int p = lbase[b] + atomicAdd(&hist[b], 1);
            int pack = ((rows[k] & (BKT_ROWS - 1)) << 18) | cols[k];
            stage[p] = make_int2(pack, __float_as_int(vals[k]));
        }
    }
    __syncthreads();

    // stream out block's private region (coalesced, full lines, write-once)
    for (int i = t; i < n; i += 1024) recs_bm[base + i] = stage[i];

    // per-block bucket offsets
    for (int i = t; i < NBKT; i += 1024)
        offM[(size_t)g * OFFW + i] = base + lbase[i];
    if (t == 0) offM[(size_t)g * OFFW + NBKT] = base + n;
}

// ---------------------------------------------------------------------------
// row_hist: block = bucket; count rows by scanning the bucket's 1465 segments
// directly from block-major records (L2/L3-resident). LDS atomics only.
// ---------------------------------------------------------------------------
__global__ __launch_bounds__(1024) void row_hist_kernel(
    const int2* __restrict__ recs_bm, const int* __restrict__ offM,
    int* __restrict__ cnt)
{
    __shared__ int lcnt[BKT_ROWS];
    int b = blockIdx.x;
    int t = threadIdx.x;
    if (t < BKT_ROWS) lcnt[t] = 0;
    __syncthreads();
    int wid = t >> 6, lane = t & 63;
    for (int g = wid; g < NBLK_BIN; g += 16) {
        size_t o = (size_t)g * OFFW + b;
        int s = offM[o], e = offM[o + 1];
        for (int i = s + lane; i < e; i += 64)
            atomicAdd(&lcnt[recs_bm[i].x >> 18], 1);
    }
    __syncthreads();
    int rowbase = b << 7;
    if (t < BKT_ROWS && rowbase + t < N_CNT) cnt[rowbase + t] = lcnt[t];
}

// ---------------------------------------------------------------------------
// 2-level exclusive scan over row counts -> rp
// ---------------------------------------------------------------------------
__global__ void scan_block_kernel(const int* __restrict__ in, int* __restrict__ out,
                                  int* __restrict__ bsum, int n) {
    __shared__ int sm[1024];
    int t = threadIdx.x;
    int i = blockIdx.x * 1024 + t;
    int v = (i < n) ? in[i] : 0;
    sm[t] = v;
    __syncthreads();
    for (int off = 1; off < 1024; off <<= 1) {
        int u = (t >= off) ? sm[t - off] : 0;
        __syncthreads();
        sm[t] += u;
        __syncthreads();
    }
    if (i < n) out[i] = sm[t] - v;
    if (t == 1023 && bsum) bsum[blockIdx.x] = sm[1023];
}

__global__ void scan_fix_kernel(int* __restrict__ rp, const int* __restrict__ boff,
                                int n, int nnz) {
    int i = blockIdx.x * 1024 + threadIdx.x;
    if (i < n) rp[i] += boff[blockIdx.x];
    if (i == 0) rp[n] = nnz;
}

// ---------------------------------------------------------------------------
// place: block = bucket; read segments directly, LDS row cursors, write CSR
// pairs. Destination = block-exclusive contiguous ~41KB region of `pairs`
// (rows of a bucket are contiguous in CSR) -> L2-resident write front.
// ---------------------------------------------------------------------------
__global__ __launch_bounds__(1024) void place_kernel(
    const int2* __restrict__ recs_bm, const int* __restrict__ offM,
    const int* __restrict__ rp, int2* __restrict__ pairs)
{
    __shared__ int cur[BKT_ROWS];
    int b = blockIdx.x;
    int t = threadIdx.x;
    int rowbase = b << 7;
    if (t < BKT_ROWS) cur[t] = (rowbase + t < N_CNT) ? rp[rowbase + t] : 0;
    __syncthreads();
    int wid = t >> 6, lane = t & 63;
    for (int g = wid; g < NBLK_BIN; g += 16) {
        size_t o = (size_t)g * OFFW + b;
        int s = offM[o], e = offM[o + 1];
        for (int i = s + lane; i < e; i += 64) {
            int2 r = recs_bm[i];
            int p = atomicAdd(&cur[r.x >> 18], 1);
            pairs[p] = make_int2(r.x & COL_MASK, r.y);
        }
    }
}

// ---------------------------------------------------------------------------
// SpMM: wave per row, lane = feature dim; unroll-8 for memory-level
// parallelism. Gather source is split (xu/xi) so layer 1 reads the concat
// virtually (no x0 materialization): xi_adj[col*64] == xi[(col-U)*64].
// mode: 0 = y & acc=, 1 = y & acc+=, 2 = acc+= only (dead y skipped).
// ---------------------------------------------------------------------------
__global__ __launch_bounds__(256) void spmm_kernel(
    const int* __restrict__ rp, const int2* __restrict__ pairs,
    const float* __restrict__ xu, const float* __restrict__ xi,
    float* __restrict__ y, float* __restrict__ acc, int mode)
{
    const float* xi_adj = xi - (size_t)U_CNT * 64;
    int wave = threadIdx.x >> 6;
    int lane = threadIdx.x & 63;
    int row = blockIdx.x * 4 + wave;
    if (row >= N_CNT) return;
    int s = rp[row];
    int e = rp[row + 1];
    float sum = 0.f;
    int i = s;
    for (; i + 7 < e; i += 8) {
        int2 p[8];
#pragma unroll
        for (int k = 0; k < 8; ++k) p[k] = pairs[i + k];
        float a[8];
#pragma unroll
        for (int k = 0; k < 8; ++k) {
            const float* base = (p[k].x < U_CNT) ? xu : xi_adj;
            a[k] = base[(size_t)p[k].x * 64 + lane];
        }
#pragma unroll
        for (int k = 0; k < 8; ++k)
            sum += __int_as_float(p[k].y) * a[k];
    }
    for (; i < e; ++i) {
        int2 pk = pairs[i];
        const float* base = (pk.x < U_CNT) ? xu : xi_adj;
        sum += __int_as_float(pk.y) * base[(size_t)pk.x * 64 + lane];
    }
    size_t o = (size_t)row * 64 + lane;
    if (mode == 0)      { y[o] = sum; acc[o] = sum; }
    else if (mode == 1) { y[o] = sum; acc[o] += sum; }
    else                {             acc[o] += sum; }
}

// ---------------------------------------------------------------------------
// Fused 2-layer MLP, wave per row; W1/W2 transposed in LDS.
// ---------------------------------------------------------------------------
__global__ __launch_bounds__(256) void mlp2_kernel(
    const float* __restrict__ xin, int nrows, float scale,
    const float* __restrict__ W1, const float* __restrict__ b1,
    const float* __restrict__ W2, const float* __restrict__ b2,
    float* __restrict__ out)
{
    __shared__ float W1T[64 * 64];
    __shared__ float W2T[64 * 64];
    __shared__ float rowbuf[4][64];
    __shared__ float hbuf[4][64];

    int t = threadIdx.x;
    for (int idx = t; idx < 4096; idx += 256) {
        int k = idx >> 6;
        int d = idx & 63;
        W1T[idx] = W1[d * 64 + k];
        W2T[idx] = W2[d * 64 + k];
    }
    __syncthreads();

    int wave = t >> 6;
    int lane = t & 63;
    float bb1 = b1[lane];
    float bb2 = b2[lane];

    for (int r = blockIdx.x * 4 + wave; r < nrows; r += gridDim.x * 4) {
        float xv = xin[(size_t)r * 64 + lane] * scale;
        rowbuf[wave][lane] = xv;
        float h = bb1;
#pragma unroll
        for (int k = 0; k < 64; ++k)
            h += rowbuf[wave][k] * W1T[k * 64 + lane];
        h = fmaxf(h, 0.f);
        hbuf[wave][lane] = h;
        float y = bb2;
#pragma unroll
        for (int k = 0; k < 64; ++k)
            y += hbuf[wave][k] * W2T[k * 64 + lane];
        out[(size_t)r * 64 + lane] = y;
    }
}

// ---------------------------------------------------------------------------

static inline int imin(int a, int b) { return a < b ? a : b; }

extern "C" void kernel_launch(void* const* d_in, const int* in_sizes, int n_in,
                              void* d_out, int out_size, void* d_ws, size_t ws_size,
                              hipStream_t stream)
{
    (void)in_sizes; (void)n_in; (void)out_size; (void)ws_size;

    const float* user_emb = (const float*)d_in[0];
    const float* item_emb = (const float*)d_in[1];
    const int*   erow     = (const int*)d_in[2];
    const int*   ecol     = (const int*)d_in[3];
    const float* evalv    = (const float*)d_in[4];
    const float* Wsg1 = (const float*)d_in[5];
    const float* bsg1 = (const float*)d_in[6];
    const float* Wsg2 = (const float*)d_in[7];
    const float* bsg2 = (const float*)d_in[8];
    const float* Wuf1 = (const float*)d_in[9];
    const float* buf1 = (const float*)d_in[10];
    const float* Wuf2 = (const float*)d_in[11];
    const float* buf2 = (const float*)d_in[12];
    const float* Wif1 = (const float*)d_in[13];
    const float* bif1 = (const float*)d_in[14];
    const float* Wif2 = (const float*)d_in[15];
    const float* bif2 = (const float*)d_in[16];

    float* out = (float*)d_out;
    const size_t XB = (size_t)N_CNT * 64;   // 9.6M floats

    // d_out transient region (dead after place; x buffers reuse it):
    //   recs_bm: 6M int2 @ [0, 12M floats) | offM: 1465*1173 ints @ [12M, ~13.72M)
    int2* recs_bm = (int2*)out;
    int*  offM    = (int*)(out + 12000000);

    // workspace (~87.6 MB):
    char* ws = (char*)d_ws;
    float* acc   = (float*)ws;                                    // 9.6M floats
    int2*  pairs = (int2*)(ws + XB * 4);                          // 6M int2
    int*   cnt   = (int*)(ws + XB * 4 + (size_t)NNZ_CNT * 8);     // 150000
    int*   rp    = cnt + N_CNT;                                   // 150001 (+pad)
    int*   bsum  = rp + N_CNT + 4;                                // 1024
    int*   boff  = bsum + 1024;                                   // 1024

    // x ping-pong: xB first (over offM tail region), then xA (over recs_bm)
    float* xA = out;
    float* xB = out + XB;

    // ---- build: bucket-sorted records -> row counts -> rp -> CSR pairs ----
    bin_sort_kernel<<<NBLK_BIN, 1024, 0, stream>>>(erow, ecol, evalv, recs_bm, offM);
    row_hist_kernel<<<NBKT, 1024, 0, stream>>>(recs_bm, offM, cnt);
    int nb = (N_CNT + 1023) / 1024;  // 147
    scan_block_kernel<<<nb, 1024, 0, stream>>>(cnt, rp, bsum, N_CNT);
    scan_block_kernel<<<1, 1024, 0, stream>>>(bsum, boff, nullptr, nb);
    scan_fix_kernel<<<nb, 1024, 0, stream>>>(rp, boff, N_CNT, NNZ_CNT);
    place_kernel<<<NBKT, 1024, 0, stream>>>(recs_bm, offM, rp, pairs);

    // ---- 3 propagation layers (layer 1 gathers the concat virtually) ----
    int sg = N_CNT / 4;  // 37500
    spmm_kernel<<<sg, 256, 0, stream>>>(rp, pairs, user_emb, item_emb, xB, acc, 0);
    spmm_kernel<<<sg, 256, 0, stream>>>(rp, pairs, xB, xB + (size_t)U_CNT * 64, xA, acc, 1);
    spmm_kernel<<<sg, 256, 0, stream>>>(rp, pairs, xA, xA + (size_t)U_CNT * 64, nullptr, acc, 2);

    // ---- MLP heads ----
    const float sc = 1.0f / 3.0f;
    int gb;
    gb = imin(1024, (N_CNT + 3) / 4);
    mlp2_kernel<<<gb, 256, 0, stream>>>(acc, N_CNT, sc, Wsg1, bsg1, Wsg2, bsg2, out);
    gb = imin(1024, (U_CNT + 3) / 4);
    mlp2_kernel<<<gb, 256, 0, stream>>>(acc, U_CNT, sc, Wuf1, buf1, Wuf2, buf2, out + XB);
    gb = imin(1024, (I_CNT + 3) / 4);
    mlp2_kernel<<<gb, 256, 0, stream>>>(acc + (size_t)U_CNT * 64, I_CNT, sc,
                                        Wif1, bif1, Wif2, bif2, out + XB + (size_t)U_CNT * 64);
}